// Round 6
// baseline (487.678 us; speedup 1.0000x reference)
//
#include <hip/hip_runtime.h>
#include <hip/hip_bf16.h>

using s16x8 = __attribute__((ext_vector_type(8))) short;   // 8 bf16 (4 VGPRs)
using f32x4 = __attribute__((ext_vector_type(4))) float;
using u16 = unsigned short;

__device__ __forceinline__ u16 f2bf(float v) {             // RNE fp32 -> bf16
    unsigned u = __float_as_uint(v);
    return (u16)((u + 0x7fffu + ((u >> 16) & 1u)) >> 16);
}
__device__ __forceinline__ float bf2f(u16 h) {
    return __uint_as_float(((unsigned)h) << 16);
}
__device__ __forceinline__ u16 f2h(float v) {              // fp32 -> fp16 RNE
    _Float16 h = (_Float16)v;
    u16 r; __builtin_memcpy(&r, &h, 2); return r;
}
__device__ __forceinline__ float h2f(u16 x) {
    _Float16 h; __builtin_memcpy(&h, &x, 2); return (float)h;
}

__device__ __forceinline__ int aswz(int row, int chunk) {  // bank-spread XOR
    return row * 32 + ((chunk ^ (row & 3) ^ ((row >> 2) & 3)) * 8);
}

// ---------------------------------------------------------------------------
// bf16x3 MFMA GEMM, tile 128 rows x 256 cols, K-step 32.
// 512 threads = 8 waves (2x4); each wave owns a 64x64 output tile.
// A hi/lo [M][K] row-major (lda) staged in LDS (double-buffered, 32 KB).
// B hi/lo transposed [256][K] read DIRECT from global (L2-resident weights) —
// no LDS for B => 2 blocks/CU instead of 1 (round-5 occupancy fix).
// OUTM: 0 = fp32 Cf, 1 = bf16 hi/lo pair, 2 = fp16 (u16) into Chi.
// ---------------------------------------------------------------------------
template<int ACT, int OUTM>
__global__ __launch_bounds__(512, 4)
void mfma3_k(const u16* __restrict__ Ahi, const u16* __restrict__ Alo, int lda,
             const u16* __restrict__ BThi, const u16* __restrict__ BTlo,
             const float* __restrict__ bias,
             float* __restrict__ Cf, u16* __restrict__ Chi, u16* __restrict__ Clo,
             int ldc, int M, int K) {
    __shared__ u16 Ah[2][128 * 32];   // 16 KB
    __shared__ u16 Al[2][128 * 32];   // 16 KB

    const int tid  = threadIdx.x;
    const int brow = blockIdx.x * 128;
    const int lane = tid & 63;
    const int wid  = tid >> 6;
    const int wr = wid >> 2, wc = wid & 3;      // 2x4 wave grid
    const int lr = lane & 15, lq = lane >> 4;

    // A staging: 512 threads cover 128 rows x 4 chunks (8 elems each)
    const int arow = tid >> 2;
    const int ac   = tid & 3;
    const int adst = aswz(arow, ac);
    const int agrow = brow + arow;
    const bool aval = (agrow < M);
    const u16* pAh = Ahi + (size_t)agrow * lda + ac * 8;
    const u16* pAl = Alo + (size_t)agrow * lda + ac * 8;

    // B fragment base (per lane): row wc*64+lr, k-offset lq*8
    const size_t bOff = (size_t)(wc * 64 + lr) * K + lq * 8;
    const u16* pBh = BThi + bOff;
    const u16* pBl = BTlo + bOff;
    const int nK16 = 16 * K;                    // row-group stride (n*16 rows)

    uint4 rAh, rAl;
    const uint4 z4 = make_uint4(0, 0, 0, 0);

    f32x4 acc[4][4] = {};

    // prologue: stage tile 0
    if (aval) {
        rAh = *reinterpret_cast<const uint4*>(pAh);
        rAl = *reinterpret_cast<const uint4*>(pAl);
    } else { rAh = z4; rAl = z4; }
    *reinterpret_cast<uint4*>(&Ah[0][adst]) = rAh;
    *reinterpret_cast<uint4*>(&Al[0][adst]) = rAl;
    __syncthreads();

    const int nt = K >> 5;
    int cur = 0;
    for (int t = 0; t < nt; ++t) {
        const int k0 = t << 5;
        if (t + 1 < nt) {                        // issue next A tile early
            if (aval) {
                rAh = *reinterpret_cast<const uint4*>(pAh + k0 + 32);
                rAl = *reinterpret_cast<const uint4*>(pAl + k0 + 32);
            }
        }

        // two n-halves to bound live B registers (<=16)
        #pragma unroll
        for (int hf = 0; hf < 2; ++hf) {
            s16x8 bhf[2], blf[2];
            #pragma unroll
            for (int n2 = 0; n2 < 2; ++n2) {
                int n = hf * 2 + n2;
                bhf[n2] = *reinterpret_cast<const s16x8*>(pBh + (size_t)n * nK16 + k0);
                blf[n2] = *reinterpret_cast<const s16x8*>(pBl + (size_t)n * nK16 + k0);
            }
            #pragma unroll
            for (int m = 0; m < 4; ++m) {
                int ar = wr * 64 + m * 16 + lr;
                int aoff = aswz(ar, lq);
                s16x8 ah = *reinterpret_cast<const s16x8*>(&Ah[cur][aoff]);
                s16x8 al = *reinterpret_cast<const s16x8*>(&Al[cur][aoff]);
                #pragma unroll
                for (int n2 = 0; n2 < 2; ++n2) {
                    int n = hf * 2 + n2;
                    acc[m][n] = __builtin_amdgcn_mfma_f32_16x16x32_bf16(ah, bhf[n2], acc[m][n], 0, 0, 0);
                    acc[m][n] = __builtin_amdgcn_mfma_f32_16x16x32_bf16(ah, blf[n2], acc[m][n], 0, 0, 0);
                    acc[m][n] = __builtin_amdgcn_mfma_f32_16x16x32_bf16(al, bhf[n2], acc[m][n], 0, 0, 0);
                }
            }
        }

        if (t + 1 < nt) {
            *reinterpret_cast<uint4*>(&Ah[cur ^ 1][adst]) = rAh;
            *reinterpret_cast<uint4*>(&Al[cur ^ 1][adst]) = rAl;
            __syncthreads();
            cur ^= 1;
        }
    }

    // epilogue: frag layout col=lane&15, row=(lane>>4)*4+r (m89-verified)
    #pragma unroll
    for (int m = 0; m < 4; ++m) {
        #pragma unroll
        for (int n = 0; n < 4; ++n) {
            #pragma unroll
            for (int r = 0; r < 4; ++r) {
                int grow = brow + wr * 64 + m * 16 + lq * 4 + r;
                if (grow >= M) continue;
                int gcol = wc * 64 + n * 16 + lr;
                float v = acc[m][n][r] + bias[gcol];
                if (ACT == 1) v = fmaxf(v, 0.f);
                size_t o = (size_t)grow * ldc + gcol;
                if (OUTM == 0) {
                    Cf[o] = v;
                } else if (OUTM == 1) {
                    u16 h = f2bf(v);
                    Chi[o] = h;
                    Clo[o] = f2bf(v - bf2f(h));
                } else {
                    Chi[o] = f2h(v);
                }
            }
        }
    }
}

// ---------------------------------------------------------------------------
// fp32 tiled GEMM (final tiny layer, N=16): C = act(A@B + bias)
// ---------------------------------------------------------------------------
template<int BM, int BN, int BK, int TM, int TN, int ACT>
__global__ __launch_bounds__((BM / TM) * (BN / TN))
void gemm_k(const float* __restrict__ A, int lda,
            const float* __restrict__ B, int ldb,
            const float* __restrict__ bias,
            float* __restrict__ C, int ldc,
            int N, int K) {
    constexpr int THREADS = (BM / TM) * (BN / TN);
    __shared__ float As[BK][BM];
    __shared__ float Bs[BK][BN + 4];
    const int tid  = threadIdx.x;
    const int brow = blockIdx.y * BM;
    const int bcol = blockIdx.x * BN;
    constexpr int TCOLS = BN / TN;
    const int tcol = tid % TCOLS;
    const int trow = tid / TCOLS;
    float acc[TM][TN] = {};
    for (int k0 = 0; k0 < K; k0 += BK) {
        #pragma unroll
        for (int i = tid; i < BM * BK; i += THREADS) {
            int r = i / BK, c = i % BK;
            int gr = brow + r;
            As[c][r] = (gr < N) ? A[(size_t)gr * lda + (k0 + c)] : 0.f;
        }
        #pragma unroll
        for (int i = tid; i < BK * BN; i += THREADS) {
            int r = i / BN, c = i % BN;
            Bs[r][c] = B[(size_t)(k0 + r) * ldb + (bcol + c)];
        }
        __syncthreads();
        #pragma unroll
        for (int kk = 0; kk < BK; kk++) {
            float a[TM], b[TN];
            #pragma unroll
            for (int m = 0; m < TM; m++) a[m] = As[kk][trow * TM + m];
            #pragma unroll
            for (int n = 0; n < TN; n++) b[n] = Bs[kk][tcol * TN + n];
            #pragma unroll
            for (int m = 0; m < TM; m++)
                #pragma unroll
                for (int n = 0; n < TN; n++)
                    acc[m][n] = fmaf(a[m], b[n], acc[m][n]);
        }
        __syncthreads();
    }
    #pragma unroll
    for (int m = 0; m < TM; m++) {
        int gr = brow + trow * TM + m;
        if (gr >= N) continue;
        #pragma unroll
        for (int n = 0; n < TN; n++) {
            int gc = bcol + tcol * TN + n;
            float v = acc[m][n] + bias[gc];
            if (ACT == 1) v = fmaxf(v, 0.f);
            else if (ACT == 2) v = tanhf(v);
            C[(size_t)gr * ldc + gc] = v;
        }
    }
}

// ---------------------------------------------------------------------------
// Layer 1 (K=16) fused with hi/lo split epilogue
// ---------------------------------------------------------------------------
__global__ __launch_bounds__(256)
void pre1_k(const float* __restrict__ x, const float* __restrict__ w1,
            const float* __restrict__ b1,
            u16* __restrict__ t0hi, u16* __restrict__ t0lo, int M) {
    __shared__ float ws[16 * 256];
    __shared__ float xs[16][17];
    const int tid = threadIdx.x;
    for (int i = tid; i < 16 * 256; i += 256) ws[i] = w1[i];
    const int r0 = blockIdx.x * 16;
    {
        int rr = tid >> 4, cc = tid & 15;
        xs[rr][cc] = (r0 + rr < M) ? x[(size_t)(r0 + rr) * 16 + cc] : 0.f;
    }
    __syncthreads();
    const int c = tid;
    const float b = b1[c];
    for (int r = 0; r < 16; r++) {
        if (r0 + r >= M) break;
        float acc = b;
        #pragma unroll
        for (int k = 0; k < 16; k++) acc = fmaf(xs[r][k], ws[k * 256 + c], acc);
        acc = fmaxf(acc, 0.f);
        u16 h = f2bf(acc);
        t0hi[(size_t)(r0 + r) * 256 + c] = h;
        t0lo[(size_t)(r0 + r) * 256 + c] = f2bf(acc - bf2f(h));
    }
}

// weight split + transpose: W [K][N] fp32 -> hiT/loT [N][K] bf16
__global__ void wsplit_k(const float* __restrict__ W, u16* __restrict__ hiT,
                         u16* __restrict__ loT, int K, int N) {
    int i = blockIdx.x * blockDim.x + threadIdx.x;
    if (i >= K * N) return;
    int n = i / K, k = i % K;
    float v = W[(size_t)k * N + n];
    u16 h = f2bf(v);
    hiT[i] = h;
    loT[i] = f2bf(v - bf2f(h));
}

// ---------------------------------------------------------------------------
// CSR-by-destination build
// ---------------------------------------------------------------------------
__global__ void hist_k(const int* __restrict__ dst, int E, int* __restrict__ counts) {
    int i = blockIdx.x * blockDim.x + threadIdx.x;
    if (i < E) atomicAdd(&counts[dst[i]], 1);
}

// hierarchical scan, stage 1: per-block exclusive scan + block sums
__global__ __launch_bounds__(256)
void scan1_k(const int* __restrict__ counts, int* __restrict__ pre,
             int* __restrict__ bsum, int n) {
    __shared__ int sh[256];
    const int t = threadIdx.x;
    const int i = blockIdx.x * 256 + t;
    int v = (i < n) ? counts[i] : 0;
    sh[t] = v;
    __syncthreads();
    #pragma unroll
    for (int d = 1; d < 256; d <<= 1) {
        int x = (t >= d) ? sh[t - d] : 0;
        __syncthreads();
        sh[t] += x;
        __syncthreads();
    }
    if (i < n) pre[i] = sh[t] - v;                 // exclusive within block
    if (t == 255) bsum[blockIdx.x] = sh[255];      // block total
}

// stage 2: single block exclusive-scans the block sums (nb <= 256)
__global__ __launch_bounds__(256)
void scan2_k(int* __restrict__ bsum, int nb) {
    __shared__ int sh[256];
    const int t = threadIdx.x;
    int v = (t < nb) ? bsum[t] : 0;
    sh[t] = v;
    __syncthreads();
    #pragma unroll
    for (int d = 1; d < 256; d <<= 1) {
        int x = (t >= d) ? sh[t - d] : 0;
        __syncthreads();
        sh[t] += x;
        __syncthreads();
    }
    if (t < nb) bsum[t] = sh[t] - v;               // exclusive block offsets
}

// stage 3: add block offsets, emit offsets + cursor (+ sentinel)
__global__ __launch_bounds__(256)
void scan3_k(const int* __restrict__ pre, const int* __restrict__ bsum,
             int* __restrict__ offsets, int* __restrict__ cursor,
             int n, int total) {
    const int i = blockIdx.x * 256 + threadIdx.x;
    if (i < n) {
        int o = pre[i] + bsum[blockIdx.x];
        offsets[i] = o;
        cursor[i]  = o;
    }
    if (i == 0) offsets[n] = total;
}

__global__ void fill_k(const int* __restrict__ src, const int* __restrict__ dst, int E,
                       int* __restrict__ cursor, int* __restrict__ sorted_src) {
    int i = blockIdx.x * blockDim.x + threadIdx.x;
    if (i < E) {
        int d = dst[i];
        int pos = atomicAdd(&cursor[d], 1);
        sorted_src[pos] = src[i];
    }
}

// ---------------------------------------------------------------------------
// Aggregate incoming messages from fp16 t rows (512 B each), fp32 accumulate,
// write hi/lo bf16 into hcat columns 256..511 (row stride 512).
// Unroll-4 over edges: 4 independent row loads in flight per wave.
// ---------------------------------------------------------------------------
__global__ void agg_k(const u16* __restrict__ t, const int* __restrict__ offsets,
                      const int* __restrict__ sorted_src,
                      u16* __restrict__ hi, u16* __restrict__ lo, int n) {
    const int node = blockIdx.x * (blockDim.x >> 6) + (threadIdx.x >> 6);
    const int lane = threadIdx.x & 63;
    if (node >= n) return;
    const int s0 = offsets[node], s1 = offsets[node + 1];

    float4 a0 = make_float4(0.f, 0.f, 0.f, 0.f);
    float4 a1 = a0, a2 = a0, a3 = a0;

    int i = s0;
    for (; i + 4 <= s1; i += 4) {
        int e0 = sorted_src[i];
        int e1 = sorted_src[i + 1];
        int e2 = sorted_src[i + 2];
        int e3 = sorted_src[i + 3];
        ushort4 v0 = *reinterpret_cast<const ushort4*>(t + (size_t)e0 * 256 + lane * 4);
        ushort4 v1 = *reinterpret_cast<const ushort4*>(t + (size_t)e1 * 256 + lane * 4);
        ushort4 v2 = *reinterpret_cast<const ushort4*>(t + (size_t)e2 * 256 + lane * 4);
        ushort4 v3 = *reinterpret_cast<const ushort4*>(t + (size_t)e3 * 256 + lane * 4);
        a0.x += h2f(v0.x); a0.y += h2f(v0.y); a0.z += h2f(v0.z); a0.w += h2f(v0.w);
        a1.x += h2f(v1.x); a1.y += h2f(v1.y); a1.z += h2f(v1.z); a1.w += h2f(v1.w);
        a2.x += h2f(v2.x); a2.y += h2f(v2.y); a2.z += h2f(v2.z); a2.w += h2f(v2.w);
        a3.x += h2f(v3.x); a3.y += h2f(v3.y); a3.z += h2f(v3.z); a3.w += h2f(v3.w);
    }
    for (; i < s1; ++i) {
        int e0 = sorted_src[i];
        ushort4 v0 = *reinterpret_cast<const ushort4*>(t + (size_t)e0 * 256 + lane * 4);
        a0.x += h2f(v0.x); a0.y += h2f(v0.y); a0.z += h2f(v0.z); a0.w += h2f(v0.w);
    }
    float4 acc;
    acc.x = (a0.x + a1.x) + (a2.x + a3.x);
    acc.y = (a0.y + a1.y) + (a2.y + a3.y);
    acc.z = (a0.z + a1.z) + (a2.z + a3.z);
    acc.w = (a0.w + a1.w) + (a2.w + a3.w);

    ushort4 h4, l4;
    h4.x = f2bf(acc.x); l4.x = f2bf(acc.x - bf2f(h4.x));
    h4.y = f2bf(acc.y); l4.y = f2bf(acc.y - bf2f(h4.y));
    h4.z = f2bf(acc.z); l4.z = f2bf(acc.z - bf2f(h4.z));
    h4.w = f2bf(acc.w); l4.w = f2bf(acc.w - bf2f(h4.w));
    size_t o = (size_t)node * 512 + 256 + (size_t)lane * 4;
    *reinterpret_cast<ushort4*>(hi + o) = h4;
    *reinterpret_cast<ushort4*>(lo + o) = l4;
}

// ---------------------------------------------------------------------------
extern "C" void kernel_launch(void* const* d_in, const int* in_sizes, int n_in,
                              void* d_out, int out_size, void* d_ws, size_t ws_size,
                              hipStream_t stream) {
    const float* x       = (const float*)d_in[0];
    const int*   edges   = (const int*)d_in[1];
    const float* pre_w1  = (const float*)d_in[2];
    const float* pre_b1  = (const float*)d_in[3];
    const float* pre_w2  = (const float*)d_in[4];
    const float* pre_b2  = (const float*)d_in[5];
    const float* conv_w  = (const float*)d_in[6];
    const float* conv_b  = (const float*)d_in[7];
    const float* post_w1 = (const float*)d_in[8];
    const float* post_b1 = (const float*)d_in[9];
    const float* post_w2 = (const float*)d_in[10];
    const float* post_b2 = (const float*)d_in[11];

    const int N = in_sizes[0] / 16;
    const int E = in_sizes[1] / 2;
    const int* src = edges;
    const int* dst = edges + E;

    // workspace layout
    u16*   hcat_hi = (u16*)d_ws;                           // N x 512
    u16*   hcat_lo = hcat_hi + (size_t)N * 512;            // N x 512
    float* Cbuf    = (float*)(hcat_lo + (size_t)N * 512);  // N x 256 f32 region
    u16*   tf16    = (u16*)Cbuf;                           // t as fp16 (dead before z)
    u16*   t0hi    = (u16*)Cbuf;                           // t0 dead before t written
    u16*   t0lo    = t0hi + (size_t)N * 256;
    u16*   w2hi    = (u16*)(Cbuf + (size_t)N * 256);
    u16*   w2lo    = w2hi + 256 * 256;
    u16*   cvhi    = w2lo + 256 * 256;
    u16*   cvlo    = cvhi + 256 * 256;
    u16*   p1hi    = cvlo + 256 * 256;
    u16*   p1lo    = p1hi + 512 * 256;
    int* offsets = (int*)(p1lo + 512 * 256);               // N+1
    int* counts  = offsets + (N + 1);                      // N
    int* cursor  = counts + N;                             // N
    int* sorted  = cursor + N;                             // E
    int* pre     = sorted + E;                             // N (scan partials)
    int* bsum    = pre + N;                                // <=256 block sums

    const dim3 blk(256);
    const dim3 g_mfma((N + 127) / 128);
    const dim3 blk_mfma(512);
    const int nsb = (N + 255) / 256;                       // scan blocks (196)

    // weight splits (transposed)
    wsplit_k<<<(256 * 256 + 255) / 256, blk, 0, stream>>>(pre_w2, w2hi, w2lo, 256, 256);
    wsplit_k<<<(256 * 256 + 255) / 256, blk, 0, stream>>>(conv_w, cvhi, cvlo, 256, 256);
    wsplit_k<<<(512 * 256 + 255) / 256, blk, 0, stream>>>(post_w1, p1hi, p1lo, 512, 256);

    // CSR by destination (independent of GEMMs)
    hipMemsetAsync(counts, 0, (size_t)N * sizeof(int), stream);
    hist_k<<<(E + 255) / 256, blk, 0, stream>>>(dst, E, counts);
    scan1_k<<<nsb, blk, 0, stream>>>(counts, pre, bsum, N);
    scan2_k<<<1, blk, 0, stream>>>(bsum, nsb);
    scan3_k<<<nsb, blk, 0, stream>>>(pre, bsum, offsets, cursor, N, E);
    fill_k<<<(E + 255) / 256, blk, 0, stream>>>(src, dst, E, cursor, sorted);

    // 1. t0 = relu(x @ pre_w1 + b1), split hi/lo
    pre1_k<<<(N + 15) / 16, blk, 0, stream>>>(x, pre_w1, pre_b1, t0hi, t0lo, N);
    // 2. h = t0 @ pre_w2 + b2 -> hcat[:, :256] (hi/lo)
    mfma3_k<0, 1><<<g_mfma, blk_mfma, 0, stream>>>(t0hi, t0lo, 256, w2hi, w2lo, pre_b2,
                                                   nullptr, hcat_hi, hcat_lo, 512, N, 256);
    // 3. t = relu(h @ conv_w + cb) -> tf16 (fp16)
    mfma3_k<1, 2><<<g_mfma, blk_mfma, 0, stream>>>(hcat_hi, hcat_lo, 512, cvhi, cvlo, conv_b,
                                                   nullptr, tf16, nullptr, 256, N, 256);
    // 4. aggregate fp16 rows -> hcat[:, 256:] (hi/lo)
    agg_k<<<(N + 3) / 4, blk, 0, stream>>>(tf16, offsets, sorted, hcat_hi, hcat_lo, N);
    // 5. z = relu(hcat @ post_w1 + b1) -> Cbuf fp32 (t dead)
    mfma3_k<1, 0><<<g_mfma, blk_mfma, 0, stream>>>(hcat_hi, hcat_lo, 512, p1hi, p1lo, post_b1,
                                                   Cbuf, nullptr, nullptr, 256, N, 512);
    // 6. out = tanh(z @ post_w2 + b2), fp32 exact final layer
    gemm_k<64, 16, 16, 4, 1, 2><<<dim3(1, (N + 63) / 64), blk, 0, stream>>>(
        Cbuf, 256, post_w2, 16, post_b2, (float*)d_out, 16, N, 256);
}

// Round 7
// 297.760 us; speedup vs baseline: 1.6378x; 1.6378x over previous
//
#include <hip/hip_runtime.h>
#include <hip/hip_bf16.h>

using f16x8 = __attribute__((ext_vector_type(8))) _Float16;  // 8 fp16 (4 VGPRs)
using f32x4 = __attribute__((ext_vector_type(4))) float;
using u16 = unsigned short;

__device__ __forceinline__ u16 f2h(float v) {              // fp32 -> fp16 RNE
    _Float16 h = (_Float16)v;
    u16 r; __builtin_memcpy(&r, &h, 2); return r;
}
__device__ __forceinline__ float h2f(u16 x) {
    _Float16 h; __builtin_memcpy(&h, &x, 2); return (float)h;
}

__device__ __forceinline__ int aswz(int row, int chunk) {  // bank-spread XOR
    return row * 32 + ((chunk ^ (row & 3) ^ ((row >> 2) & 3)) * 8);
}

// ---------------------------------------------------------------------------
// fp16 MFMA GEMM (fp32 accumulate), tile 128 rows x 256 cols, K-step 32.
// 512 threads = 8 waves (2x4); each wave owns a 64x64 output tile.
// A fp16 [M][K] row-major (lda), staged in LDS double-buffered (16 KB).
// B fp16 transposed [256][K] row-major, staged in LDS double-buffered (32 KB).
// Reg-staged global loads for tile t+1 issued before compute of tile t;
// ONE barrier per K-step (round-5-proven structure). 48 KB LDS total.
// OUTM: 0 = fp32 Cf, 1 = fp16 Ch.
// ---------------------------------------------------------------------------
template<int ACT, int OUTM>
__global__ __launch_bounds__(512, 4)
void mfma_k(const u16* __restrict__ A, int lda,
            const u16* __restrict__ BT,
            const float* __restrict__ bias,
            float* __restrict__ Cf, u16* __restrict__ Ch,
            int ldc, int M, int K) {
    __shared__ u16 As[2][128 * 32];   // 16 KB
    __shared__ u16 Bs[2][256 * 32];   // 32 KB

    const int tid  = threadIdx.x;
    const int brow = blockIdx.x * 128;
    const int lane = tid & 63;
    const int wid  = tid >> 6;
    const int wr = wid >> 2, wc = wid & 3;      // 2x4 wave grid
    const int lr = lane & 15, lq = lane >> 4;

    // A staging: 512 threads cover 128 rows x 4 chunks (8 elems)
    const int arow = tid >> 2;
    const int ac   = tid & 3;
    const int adst = aswz(arow, ac);
    const int agrow = brow + arow;
    const bool aval = (agrow < M);
    const u16* pA = A + (size_t)agrow * lda + ac * 8;

    // B staging: 1024 chunks -> 2 per thread (rows r and r+128)
    const int br0 = tid >> 2;
    const int br1 = 128 + br0;
    const int bdst0 = aswz(br0, ac);
    const int bdst1 = aswz(br1, ac);
    const u16* pB0 = BT + (size_t)br0 * K + ac * 8;
    const u16* pB1 = BT + (size_t)br1 * K + ac * 8;

    uint4 rA, rB0, rB1;
    const uint4 z4 = make_uint4(0, 0, 0, 0);

#define LOADT(k0)                                                              \
    do {                                                                       \
        rA  = aval ? *reinterpret_cast<const uint4*>(pA + (k0)) : z4;          \
        rB0 = *reinterpret_cast<const uint4*>(pB0 + (k0));                     \
        rB1 = *reinterpret_cast<const uint4*>(pB1 + (k0));                     \
    } while (0)

#define WRITET(b)                                                              \
    do {                                                                       \
        *reinterpret_cast<uint4*>(&As[b][adst])  = rA;                         \
        *reinterpret_cast<uint4*>(&Bs[b][bdst0]) = rB0;                        \
        *reinterpret_cast<uint4*>(&Bs[b][bdst1]) = rB1;                        \
    } while (0)

    f32x4 acc[4][4] = {};

    LOADT(0);
    WRITET(0);
    __syncthreads();

    const int nt = K >> 5;
    int cur = 0;
    for (int t = 0; t < nt; ++t) {
        if (t + 1 < nt) LOADT((t + 1) << 5);

        f16x8 bf[4];
        #pragma unroll
        for (int n = 0; n < 4; ++n) {
            int bc = wc * 64 + n * 16 + lr;
            bf[n] = *reinterpret_cast<const f16x8*>(&Bs[cur][aswz(bc, lq)]);
        }
        #pragma unroll
        for (int m = 0; m < 4; ++m) {
            int ar = wr * 64 + m * 16 + lr;
            f16x8 af = *reinterpret_cast<const f16x8*>(&As[cur][aswz(ar, lq)]);
            #pragma unroll
            for (int n = 0; n < 4; ++n)
                acc[m][n] = __builtin_amdgcn_mfma_f32_16x16x32_f16(af, bf[n], acc[m][n], 0, 0, 0);
        }

        if (t + 1 < nt) {
            WRITET(cur ^ 1);      // compiler inserts vmcnt before ds_writes
            __syncthreads();      // single barrier per K-step
            cur ^= 1;
        }
    }
#undef LOADT
#undef WRITET

    // epilogue: frag layout col=lane&15, row=(lane>>4)*4+r (m89-verified)
    #pragma unroll
    for (int m = 0; m < 4; ++m) {
        #pragma unroll
        for (int n = 0; n < 4; ++n) {
            #pragma unroll
            for (int r = 0; r < 4; ++r) {
                int grow = brow + wr * 64 + m * 16 + lq * 4 + r;
                if (grow >= M) continue;
                int gcol = wc * 64 + n * 16 + lr;
                float v = acc[m][n][r] + bias[gcol];
                if (ACT == 1) v = fmaxf(v, 0.f);
                size_t o = (size_t)grow * ldc + gcol;
                if (OUTM == 0) Cf[o] = v;
                else           Ch[o] = f2h(v);
            }
        }
    }
}

// ---------------------------------------------------------------------------
// fp32 tiled GEMM (final tiny layer, N=16): C = act(A@B + bias)
// ---------------------------------------------------------------------------
template<int BM, int BN, int BK, int TM, int TN, int ACT>
__global__ __launch_bounds__((BM / TM) * (BN / TN))
void gemm_k(const float* __restrict__ A, int lda,
            const float* __restrict__ B, int ldb,
            const float* __restrict__ bias,
            float* __restrict__ C, int ldc,
            int N, int K) {
    constexpr int THREADS = (BM / TM) * (BN / TN);
    __shared__ float As[BK][BM];
    __shared__ float Bs[BK][BN + 4];
    const int tid  = threadIdx.x;
    const int brow = blockIdx.y * BM;
    const int bcol = blockIdx.x * BN;
    constexpr int TCOLS = BN / TN;
    const int tcol = tid % TCOLS;
    const int trow = tid / TCOLS;
    float acc[TM][TN] = {};
    for (int k0 = 0; k0 < K; k0 += BK) {
        #pragma unroll
        for (int i = tid; i < BM * BK; i += THREADS) {
            int r = i / BK, c = i % BK;
            int gr = brow + r;
            As[c][r] = (gr < N) ? A[(size_t)gr * lda + (k0 + c)] : 0.f;
        }
        #pragma unroll
        for (int i = tid; i < BK * BN; i += THREADS) {
            int r = i / BN, c = i % BN;
            Bs[r][c] = B[(size_t)(k0 + r) * ldb + (bcol + c)];
        }
        __syncthreads();
        #pragma unroll
        for (int kk = 0; kk < BK; kk++) {
            float a[TM], b[TN];
            #pragma unroll
            for (int m = 0; m < TM; m++) a[m] = As[kk][trow * TM + m];
            #pragma unroll
            for (int n = 0; n < TN; n++) b[n] = Bs[kk][tcol * TN + n];
            #pragma unroll
            for (int m = 0; m < TM; m++)
                #pragma unroll
                for (int n = 0; n < TN; n++)
                    acc[m][n] = fmaf(a[m], b[n], acc[m][n]);
        }
        __syncthreads();
    }
    #pragma unroll
    for (int m = 0; m < TM; m++) {
        int gr = brow + trow * TM + m;
        if (gr >= N) continue;
        #pragma unroll
        for (int n = 0; n < TN; n++) {
            int gc = bcol + tcol * TN + n;
            float v = acc[m][n] + bias[gc];
            if (ACT == 1) v = fmaxf(v, 0.f);
            else if (ACT == 2) v = tanhf(v);
            C[(size_t)gr * ldc + gc] = v;
        }
    }
}

// ---------------------------------------------------------------------------
// Layer 1 (K=16): t0 = relu(x @ pre_w1 + b1) -> fp16
// ---------------------------------------------------------------------------
__global__ __launch_bounds__(256)
void pre1_k(const float* __restrict__ x, const float* __restrict__ w1,
            const float* __restrict__ b1,
            u16* __restrict__ t0, int M) {
    __shared__ float ws[16 * 256];
    __shared__ float xs[16][17];
    const int tid = threadIdx.x;
    for (int i = tid; i < 16 * 256; i += 256) ws[i] = w1[i];
    const int r0 = blockIdx.x * 16;
    {
        int rr = tid >> 4, cc = tid & 15;
        xs[rr][cc] = (r0 + rr < M) ? x[(size_t)(r0 + rr) * 16 + cc] : 0.f;
    }
    __syncthreads();
    const int c = tid;
    const float b = b1[c];
    for (int r = 0; r < 16; r++) {
        if (r0 + r >= M) break;
        float acc = b;
        #pragma unroll
        for (int k = 0; k < 16; k++) acc = fmaf(xs[r][k], ws[k * 256 + c], acc);
        t0[(size_t)(r0 + r) * 256 + c] = f2h(fmaxf(acc, 0.f));
    }
}

// weight transpose + fp16 cast: W [K][N] fp32 -> WT [N][K] fp16
__global__ void wsplit_k(const float* __restrict__ W, u16* __restrict__ WT,
                         int K, int N) {
    int i = blockIdx.x * blockDim.x + threadIdx.x;
    if (i >= K * N) return;
    int n = i / K, k = i % K;
    WT[i] = f2h(W[(size_t)k * N + n]);
}

// ---------------------------------------------------------------------------
// CSR-by-destination build
// ---------------------------------------------------------------------------
__global__ void hist_k(const int* __restrict__ dst, int E, int* __restrict__ counts) {
    int i = blockIdx.x * blockDim.x + threadIdx.x;
    if (i < E) atomicAdd(&counts[dst[i]], 1);
}

// hierarchical scan, stage 1: per-block exclusive scan + block sums
__global__ __launch_bounds__(256)
void scan1_k(const int* __restrict__ counts, int* __restrict__ pre,
             int* __restrict__ bsum, int n) {
    __shared__ int sh[256];
    const int t = threadIdx.x;
    const int i = blockIdx.x * 256 + t;
    int v = (i < n) ? counts[i] : 0;
    sh[t] = v;
    __syncthreads();
    #pragma unroll
    for (int d = 1; d < 256; d <<= 1) {
        int x = (t >= d) ? sh[t - d] : 0;
        __syncthreads();
        sh[t] += x;
        __syncthreads();
    }
    if (i < n) pre[i] = sh[t] - v;
    if (t == 255) bsum[blockIdx.x] = sh[255];
}

// stage 2: single block exclusive-scans the block sums (nb <= 256)
__global__ __launch_bounds__(256)
void scan2_k(int* __restrict__ bsum, int nb) {
    __shared__ int sh[256];
    const int t = threadIdx.x;
    int v = (t < nb) ? bsum[t] : 0;
    sh[t] = v;
    __syncthreads();
    #pragma unroll
    for (int d = 1; d < 256; d <<= 1) {
        int x = (t >= d) ? sh[t - d] : 0;
        __syncthreads();
        sh[t] += x;
        __syncthreads();
    }
    if (t < nb) bsum[t] = sh[t] - v;
}

// stage 3: add block offsets, emit offsets + cursor (+ sentinel)
__global__ __launch_bounds__(256)
void scan3_k(const int* __restrict__ pre, const int* __restrict__ bsum,
             int* __restrict__ offsets, int* __restrict__ cursor,
             int n, int total) {
    const int i = blockIdx.x * 256 + threadIdx.x;
    if (i < n) {
        int o = pre[i] + bsum[blockIdx.x];
        offsets[i] = o;
        cursor[i]  = o;
    }
    if (i == 0) offsets[n] = total;
}

__global__ void fill_k(const int* __restrict__ src, const int* __restrict__ dst, int E,
                       int* __restrict__ cursor, int* __restrict__ sorted_src) {
    int i = blockIdx.x * blockDim.x + threadIdx.x;
    if (i < E) {
        int d = dst[i];
        int pos = atomicAdd(&cursor[d], 1);
        sorted_src[pos] = src[i];
    }
}

// ---------------------------------------------------------------------------
// Aggregate incoming messages from fp16 t rows (512 B each), fp32 accumulate,
// write fp16 into hcat columns 256..511 (row stride 512).
// Unroll-4 over edges: 4 independent row loads in flight per wave.
// ---------------------------------------------------------------------------
__global__ void agg_k(const u16* __restrict__ t, const int* __restrict__ offsets,
                      const int* __restrict__ sorted_src,
                      u16* __restrict__ out, int n) {
    const int node = blockIdx.x * (blockDim.x >> 6) + (threadIdx.x >> 6);
    const int lane = threadIdx.x & 63;
    if (node >= n) return;
    const int s0 = offsets[node], s1 = offsets[node + 1];

    float4 a0 = make_float4(0.f, 0.f, 0.f, 0.f);
    float4 a1 = a0, a2 = a0, a3 = a0;

    int i = s0;
    for (; i + 4 <= s1; i += 4) {
        int e0 = sorted_src[i];
        int e1 = sorted_src[i + 1];
        int e2 = sorted_src[i + 2];
        int e3 = sorted_src[i + 3];
        ushort4 v0 = *reinterpret_cast<const ushort4*>(t + (size_t)e0 * 256 + lane * 4);
        ushort4 v1 = *reinterpret_cast<const ushort4*>(t + (size_t)e1 * 256 + lane * 4);
        ushort4 v2 = *reinterpret_cast<const ushort4*>(t + (size_t)e2 * 256 + lane * 4);
        ushort4 v3 = *reinterpret_cast<const ushort4*>(t + (size_t)e3 * 256 + lane * 4);
        a0.x += h2f(v0.x); a0.y += h2f(v0.y); a0.z += h2f(v0.z); a0.w += h2f(v0.w);
        a1.x += h2f(v1.x); a1.y += h2f(v1.y); a1.z += h2f(v1.z); a1.w += h2f(v1.w);
        a2.x += h2f(v2.x); a2.y += h2f(v2.y); a2.z += h2f(v2.z); a2.w += h2f(v2.w);
        a3.x += h2f(v3.x); a3.y += h2f(v3.y); a3.z += h2f(v3.z); a3.w += h2f(v3.w);
    }
    for (; i < s1; ++i) {
        int e0 = sorted_src[i];
        ushort4 v0 = *reinterpret_cast<const ushort4*>(t + (size_t)e0 * 256 + lane * 4);
        a0.x += h2f(v0.x); a0.y += h2f(v0.y); a0.z += h2f(v0.z); a0.w += h2f(v0.w);
    }
    float4 acc;
    acc.x = (a0.x + a1.x) + (a2.x + a3.x);
    acc.y = (a0.y + a1.y) + (a2.y + a3.y);
    acc.z = (a0.z + a1.z) + (a2.z + a3.z);
    acc.w = (a0.w + a1.w) + (a2.w + a3.w);

    ushort4 h4;
    h4.x = f2h(acc.x); h4.y = f2h(acc.y); h4.z = f2h(acc.z); h4.w = f2h(acc.w);
    *reinterpret_cast<ushort4*>(out + (size_t)node * 512 + 256 + (size_t)lane * 4) = h4;
}

// ---------------------------------------------------------------------------
extern "C" void kernel_launch(void* const* d_in, const int* in_sizes, int n_in,
                              void* d_out, int out_size, void* d_ws, size_t ws_size,
                              hipStream_t stream) {
    const float* x       = (const float*)d_in[0];
    const int*   edges   = (const int*)d_in[1];
    const float* pre_w1  = (const float*)d_in[2];
    const float* pre_b1  = (const float*)d_in[3];
    const float* pre_w2  = (const float*)d_in[4];
    const float* pre_b2  = (const float*)d_in[5];
    const float* conv_w  = (const float*)d_in[6];
    const float* conv_b  = (const float*)d_in[7];
    const float* post_w1 = (const float*)d_in[8];
    const float* post_b1 = (const float*)d_in[9];
    const float* post_w2 = (const float*)d_in[10];
    const float* post_b2 = (const float*)d_in[11];

    const int N = in_sizes[0] / 16;
    const int E = in_sizes[1] / 2;
    const int* src = edges;
    const int* dst = edges + E;

    // workspace layout (~158 MB)
    u16*   hcat = (u16*)d_ws;                              // N x 512 fp16 (h || agg)
    u16*   t0   = hcat + (size_t)N * 512;                  // N x 256 fp16
    u16*   tf16 = t0 + (size_t)N * 256;                    // N x 256 fp16
    float* zbuf = (float*)(tf16 + (size_t)N * 256);        // N x 256 fp32
    u16*   w2T  = (u16*)(zbuf + (size_t)N * 256);          // 256 x 256 fp16
    u16*   cvT  = w2T + 256 * 256;                         // 256 x 256 fp16
    u16*   p1T  = cvT + 256 * 256;                         // 256 x 512 fp16
    int* offsets = (int*)(p1T + 256 * 512);                // N+1
    int* counts  = offsets + (N + 1);                      // N
    int* cursor  = counts + N;                             // N
    int* sorted  = cursor + N;                             // E
    int* pre     = sorted + E;                             // N (scan partials)
    int* bsum    = pre + N;                                // <=256 block sums

    const dim3 blk(256);
    const dim3 g_mfma((N + 127) / 128);
    const dim3 blk_mfma(512);
    const int nsb = (N + 255) / 256;

    // weight transposes (fp16)
    wsplit_k<<<(256 * 256 + 255) / 256, blk, 0, stream>>>(pre_w2, w2T, 256, 256);
    wsplit_k<<<(256 * 256 + 255) / 256, blk, 0, stream>>>(conv_w, cvT, 256, 256);
    wsplit_k<<<(512 * 256 + 255) / 256, blk, 0, stream>>>(post_w1, p1T, 512, 256);

    // CSR by destination (independent of GEMMs)
    hipMemsetAsync(counts, 0, (size_t)N * sizeof(int), stream);
    hist_k<<<(E + 255) / 256, blk, 0, stream>>>(dst, E, counts);
    scan1_k<<<nsb, blk, 0, stream>>>(counts, pre, bsum, N);
    scan2_k<<<1, blk, 0, stream>>>(bsum, nsb);
    scan3_k<<<nsb, blk, 0, stream>>>(pre, bsum, offsets, cursor, N, E);
    fill_k<<<(E + 255) / 256, blk, 0, stream>>>(src, dst, E, cursor, sorted);

    // 1. t0 = relu(x @ pre_w1 + b1) -> fp16
    pre1_k<<<(N + 15) / 16, blk, 0, stream>>>(x, pre_w1, pre_b1, t0, N);
    // 2. h = t0 @ pre_w2 + b2 -> hcat[:, :256] fp16
    mfma_k<0, 1><<<g_mfma, blk_mfma, 0, stream>>>(t0, 256, w2T, pre_b2,
                                                  nullptr, hcat, 512, N, 256);
    // 3. t = relu(h @ conv_w + cb) -> tf16
    mfma_k<1, 1><<<g_mfma, blk_mfma, 0, stream>>>(hcat, 512, cvT, conv_b,
                                                  nullptr, tf16, 256, N, 256);
    // 4. aggregate fp16 rows -> hcat[:, 256:] fp16
    agg_k<<<(N + 3) / 4, blk, 0, stream>>>(tf16, offsets, sorted, hcat, N);
    // 5. z = relu(hcat @ post_w1 + b1) -> zbuf fp32
    mfma_k<1, 0><<<g_mfma, blk_mfma, 0, stream>>>(hcat, 512, p1T, post_b1,
                                                  zbuf, nullptr, 256, N, 512);
    // 6. out = tanh(z @ post_w2 + b2), fp32 exact final layer
    gemm_k<64, 16, 16, 4, 1, 2><<<dim3(1, (N + 63) / 64), blk, 0, stream>>>(
        zbuf, 256, post_w2, 16, post_b2, (float*)d_out, 16, N, 256);
}

// Round 8
// 281.358 us; speedup vs baseline: 1.7333x; 1.0583x over previous
//
#include <hip/hip_runtime.h>
#include <hip/hip_bf16.h>

using f16x8 = __attribute__((ext_vector_type(8))) _Float16;  // 8 fp16 (4 VGPRs)
using f32x4 = __attribute__((ext_vector_type(4))) float;
using u16 = unsigned short;

__device__ __forceinline__ u16 f2h(float v) {
    _Float16 h = (_Float16)v;
    u16 r; __builtin_memcpy(&r, &h, 2); return r;
}
__device__ __forceinline__ float h2f(u16 x) {
    _Float16 h; __builtin_memcpy(&h, &x, 2); return (float)h;
}

// bank-decorrelation XOR: chunk permutation within a row's 4x16B chunks
__device__ __forceinline__ int fsw(int row) { return (row & 3) ^ ((row >> 2) & 3); }
// LDS elem offset of frag chunk kq for local row (linear [row][32] fp16 tile)
__device__ __forceinline__ int aoff(int row, int kq) {
    return row * 32 + ((kq ^ fsw(row)) * 8);
}

// async global->LDS DMA, 16B per lane; LDS dest = wave-uniform base + lane*16
__device__ __forceinline__ void gl16(const u16* g, const u16* l) {
    __builtin_amdgcn_global_load_lds(
        (const __attribute__((address_space(1))) unsigned int*)g,
        (__attribute__((address_space(3))) unsigned int*)l, 16, 0, 0);
}

// ---------------------------------------------------------------------------
// fp16 MFMA GEMM (fp32 accumulate), m97-style: tile 128x128, BK=32,
// 256 threads = 4 waves (2x2), each wave owns a 64x64 output tile.
// A fp16 [Mpad][lda]; BT fp16 [256][K] (transposed weights).
// Staging via global_load_lds dwordx4 into linear LDS; the chunk-XOR swizzle
// is applied on the GLOBAL source address and again on the ds_read (rule #21).
// LDS double-buffered (32 KB), one barrier per K-step; ~3 blocks/CU resident.
// OUTM: 0 = fp32 Cf, 1 = fp16 Ch.
// ---------------------------------------------------------------------------
template<int ACT, int OUTM>
__global__ __launch_bounds__(256, 4)
void mfma_k(const u16* __restrict__ A, int lda,
            const u16* __restrict__ BT,
            const float* __restrict__ bias,
            float* __restrict__ Cf, u16* __restrict__ Ch,
            int ldc, int M, int K) {
    __shared__ u16 As[2][128 * 32];   // 8 KB x2
    __shared__ u16 Bs[2][128 * 32];   // 8 KB x2

    const int tid  = threadIdx.x;
    const int brow = blockIdx.x * 128;
    const int bcol = blockIdx.y * 128;
    const int lane = tid & 63;
    const int w    = tid >> 6;               // 0..3
    const int wr = w >> 1, wc = w & 1;       // 2x2 wave grid
    const int lr = lane & 15, lq = lane >> 4;

    // staging geometry: 8 regions of 16 rows x 1KB; wave w owns regions w, 4+w
    const int r0 = w, r1 = 4 + w;
    const int row0 = r0 * 16 + (lane >> 2);
    const int row1 = r1 * 16 + (lane >> 2);
    const int s    = lane & 3;               // linear 16B slot within row
    const int c0 = s ^ fsw(row0);            // source chunk (pre-swizzled)
    const int c1 = s ^ fsw(row1);
    const u16* gA0 = A  + (size_t)(brow + row0) * lda + c0 * 8;
    const u16* gA1 = A  + (size_t)(brow + row1) * lda + c1 * 8;
    const u16* gB0 = BT + (size_t)(bcol + row0) * K   + c0 * 8;
    const u16* gB1 = BT + (size_t)(bcol + row1) * K   + c1 * 8;

    f32x4 acc[4][4] = {};

#define STAGE(buf, koff)                                                       \
    do {                                                                       \
        gl16(gA0 + (koff), &As[buf][r0 * 512]);                                \
        gl16(gA1 + (koff), &As[buf][r1 * 512]);                                \
        gl16(gB0 + (koff), &Bs[buf][r0 * 512]);                                \
        gl16(gB1 + (koff), &Bs[buf][r1 * 512]);                                \
    } while (0)

    STAGE(0, 0);
    __syncthreads();

    const int nt = K >> 5;
    int cur = 0;
    for (int t = 0; t < nt; ++t) {
        if (t + 1 < nt) STAGE(cur ^ 1, (t + 1) * 32);

        f16x8 bf[4];
        #pragma unroll
        for (int n = 0; n < 4; ++n)
            bf[n] = *reinterpret_cast<const f16x8*>(&Bs[cur][aoff(wc * 64 + n * 16 + lr, lq)]);
        #pragma unroll
        for (int m = 0; m < 4; ++m) {
            f16x8 af = *reinterpret_cast<const f16x8*>(&As[cur][aoff(wr * 64 + m * 16 + lr, lq)]);
            #pragma unroll
            for (int n = 0; n < 4; ++n)
                acc[m][n] = __builtin_amdgcn_mfma_f32_16x16x32_f16(af, bf[n], acc[m][n], 0, 0, 0);
        }

        if (t + 1 < nt) {
            __syncthreads();     // all reads of cur done AND DMA of cur^1 landed
            cur ^= 1;
        }
    }
#undef STAGE

    // epilogue: frag layout col=lane&15, row=(lane>>4)*4+r (m89-verified)
    #pragma unroll
    for (int m = 0; m < 4; ++m) {
        #pragma unroll
        for (int n = 0; n < 4; ++n) {
            #pragma unroll
            for (int r = 0; r < 4; ++r) {
                int grow = brow + wr * 64 + m * 16 + lq * 4 + r;
                if (grow >= M) continue;
                int gcol = bcol + wc * 64 + n * 16 + lr;
                float v = acc[m][n][r] + bias[gcol];
                if (ACT == 1) v = fmaxf(v, 0.f);
                size_t o = (size_t)grow * ldc + gcol;
                if (OUTM == 0) Cf[o] = v;
                else           Ch[o] = f2h(v);
            }
        }
    }
}

// ---------------------------------------------------------------------------
// Final layer fused: out = tanh(Z @ p2 + b2), Z fp16 [*][256], p2T fp16 [16][256].
// 256 threads = 4 waves; block tile 256 rows x 16 cols; B held in 32 VGPRs;
// K-loop fully unrolled (8 steps) so all reg-array indices are static.
// ---------------------------------------------------------------------------
__global__ __launch_bounds__(256, 4)
void post2_k(const u16* __restrict__ Z, const u16* __restrict__ P2T,
             const float* __restrict__ b2, float* __restrict__ out, int M) {
    __shared__ u16 As[2][256 * 32];   // 16 KB x2

    const int tid  = threadIdx.x;
    const int brow = blockIdx.x * 256;
    const int lane = tid & 63;
    const int w    = tid >> 6;
    const int lr = lane & 15, lq = lane >> 4;

    // B fragments (entire 16x256) in registers, loaded once, coalesced-ish
    f16x8 bfr[8];
    #pragma unroll
    for (int kk = 0; kk < 8; ++kk)
        bfr[kk] = *reinterpret_cast<const f16x8*>(P2T + lr * 256 + kk * 32 + lq * 8);

    // staging: 16 regions of 16 rows; wave w owns regions w, 4+w, 8+w, 12+w
    int rows[4]; int cs[4]; const u16* gz[4];
    #pragma unroll
    for (int i = 0; i < 4; ++i) {
        int r = i * 4 + w;
        rows[i] = r * 16 + (lane >> 2);
        cs[i]   = (lane & 3) ^ fsw(rows[i]);
        gz[i]   = Z + (size_t)(brow + rows[i]) * 256 + cs[i] * 8;
    }

#define STAGEZ(buf, koff)                                                      \
    do {                                                                       \
        _Pragma("unroll")                                                      \
        for (int i = 0; i < 4; ++i)                                            \
            gl16(gz[i] + (koff), &As[buf][(i * 4 + w) * 512]);                 \
    } while (0)

    f32x4 acc[4] = {};

    STAGEZ(0, 0);
    __syncthreads();

    #pragma unroll
    for (int t = 0; t < 8; ++t) {
        if (t < 7) STAGEZ((t + 1) & 1, (t + 1) * 32);
        #pragma unroll
        for (int m = 0; m < 4; ++m) {
            f16x8 af = *reinterpret_cast<const f16x8*>(&As[t & 1][aoff(w * 64 + m * 16 + lr, lq)]);
            acc[m] = __builtin_amdgcn_mfma_f32_16x16x32_f16(af, bfr[t], acc[m], 0, 0, 0);
        }
        if (t < 7) __syncthreads();
    }
#undef STAGEZ

    const float b = b2[lr];
    #pragma unroll
    for (int m = 0; m < 4; ++m) {
        #pragma unroll
        for (int r = 0; r < 4; ++r) {
            int grow = brow + w * 64 + m * 16 + lq * 4 + r;
            if (grow >= M) continue;
            out[(size_t)grow * 16 + lr] = tanhf(acc[m][r] + b);
        }
    }
}

// ---------------------------------------------------------------------------
// Layer 1 (K=16): t0 = relu(x @ pre_w1 + b1) -> fp16
// ---------------------------------------------------------------------------
__global__ __launch_bounds__(256)
void pre1_k(const float* __restrict__ x, const float* __restrict__ w1,
            const float* __restrict__ b1,
            u16* __restrict__ t0, int M) {
    __shared__ float ws[16 * 256];
    __shared__ float xs[16][17];
    const int tid = threadIdx.x;
    for (int i = tid; i < 16 * 256; i += 256) ws[i] = w1[i];
    const int r0 = blockIdx.x * 16;
    {
        int rr = tid >> 4, cc = tid & 15;
        xs[rr][cc] = (r0 + rr < M) ? x[(size_t)(r0 + rr) * 16 + cc] : 0.f;
    }
    __syncthreads();
    const int c = tid;
    const float b = b1[c];
    for (int r = 0; r < 16; r++) {
        if (r0 + r >= M) break;
        float acc = b;
        #pragma unroll
        for (int k = 0; k < 16; k++) acc = fmaf(xs[r][k], ws[k * 256 + c], acc);
        t0[(size_t)(r0 + r) * 256 + c] = f2h(fmaxf(acc, 0.f));
    }
}

// weight transpose + fp16 cast: W [K][N] fp32 -> WT [N][K] fp16
__global__ void wsplit_k(const float* __restrict__ W, u16* __restrict__ WT,
                         int K, int N) {
    int i = blockIdx.x * blockDim.x + threadIdx.x;
    if (i >= K * N) return;
    int n = i / K, k = i % K;
    WT[i] = f2h(W[(size_t)k * N + n]);
}

// ---------------------------------------------------------------------------
// CSR-by-destination build
// ---------------------------------------------------------------------------
__global__ void hist_k(const int* __restrict__ dst, int E, int* __restrict__ counts) {
    int i = blockIdx.x * blockDim.x + threadIdx.x;
    if (i < E) atomicAdd(&counts[dst[i]], 1);
}

__global__ __launch_bounds__(256)
void scan1_k(const int* __restrict__ counts, int* __restrict__ pre,
             int* __restrict__ bsum, int n) {
    __shared__ int sh[256];
    const int t = threadIdx.x;
    const int i = blockIdx.x * 256 + t;
    int v = (i < n) ? counts[i] : 0;
    sh[t] = v;
    __syncthreads();
    #pragma unroll
    for (int d = 1; d < 256; d <<= 1) {
        int x = (t >= d) ? sh[t - d] : 0;
        __syncthreads();
        sh[t] += x;
        __syncthreads();
    }
    if (i < n) pre[i] = sh[t] - v;
    if (t == 255) bsum[blockIdx.x] = sh[255];
}

__global__ __launch_bounds__(256)
void scan2_k(int* __restrict__ bsum, int nb) {
    __shared__ int sh[256];
    const int t = threadIdx.x;
    int v = (t < nb) ? bsum[t] : 0;
    sh[t] = v;
    __syncthreads();
    #pragma unroll
    for (int d = 1; d < 256; d <<= 1) {
        int x = (t >= d) ? sh[t - d] : 0;
        __syncthreads();
        sh[t] += x;
        __syncthreads();
    }
    if (t < nb) bsum[t] = sh[t] - v;
}

__global__ __launch_bounds__(256)
void scan3_k(const int* __restrict__ pre, const int* __restrict__ bsum,
             int* __restrict__ offsets, int* __restrict__ cursor,
             int n, int total) {
    const int i = blockIdx.x * 256 + threadIdx.x;
    if (i < n) {
        int o = pre[i] + bsum[blockIdx.x];
        offsets[i] = o;
        cursor[i]  = o;
    }
    if (i == 0) offsets[n] = total;
}

__global__ void fill_k(const int* __restrict__ src, const int* __restrict__ dst, int E,
                       int* __restrict__ cursor, int* __restrict__ sorted_src) {
    int i = blockIdx.x * blockDim.x + threadIdx.x;
    if (i < E) {
        int d = dst[i];
        int pos = atomicAdd(&cursor[d], 1);
        sorted_src[pos] = src[i];
    }
}

// ---------------------------------------------------------------------------
// Aggregate fp16 message rows (512 B), fp32 accumulate, fp16 out into
// hcat cols 256..511. Unroll-4 for 4 independent row loads in flight.
// ---------------------------------------------------------------------------
__global__ void agg_k(const u16* __restrict__ t, const int* __restrict__ offsets,
                      const int* __restrict__ sorted_src,
                      u16* __restrict__ out, int n) {
    const int node = blockIdx.x * (blockDim.x >> 6) + (threadIdx.x >> 6);
    const int lane = threadIdx.x & 63;
    if (node >= n) return;
    const int s0 = offsets[node], s1 = offsets[node + 1];

    float4 a0 = make_float4(0.f, 0.f, 0.f, 0.f);
    float4 a1 = a0, a2 = a0, a3 = a0;

    int i = s0;
    for (; i + 4 <= s1; i += 4) {
        int e0 = sorted_src[i];
        int e1 = sorted_src[i + 1];
        int e2 = sorted_src[i + 2];
        int e3 = sorted_src[i + 3];
        ushort4 v0 = *reinterpret_cast<const ushort4*>(t + (size_t)e0 * 256 + lane * 4);
        ushort4 v1 = *reinterpret_cast<const ushort4*>(t + (size_t)e1 * 256 + lane * 4);
        ushort4 v2 = *reinterpret_cast<const ushort4*>(t + (size_t)e2 * 256 + lane * 4);
        ushort4 v3 = *reinterpret_cast<const ushort4*>(t + (size_t)e3 * 256 + lane * 4);
        a0.x += h2f(v0.x); a0.y += h2f(v0.y); a0.z += h2f(v0.z); a0.w += h2f(v0.w);
        a1.x += h2f(v1.x); a1.y += h2f(v1.y); a1.z += h2f(v1.z); a1.w += h2f(v1.w);
        a2.x += h2f(v2.x); a2.y += h2f(v2.y); a2.z += h2f(v2.z); a2.w += h2f(v2.w);
        a3.x += h2f(v3.x); a3.y += h2f(v3.y); a3.z += h2f(v3.z); a3.w += h2f(v3.w);
    }
    for (; i < s1; ++i) {
        int e0 = sorted_src[i];
        ushort4 v0 = *reinterpret_cast<const ushort4*>(t + (size_t)e0 * 256 + lane * 4);
        a0.x += h2f(v0.x); a0.y += h2f(v0.y); a0.z += h2f(v0.z); a0.w += h2f(v0.w);
    }
    float4 acc;
    acc.x = (a0.x + a1.x) + (a2.x + a3.x);
    acc.y = (a0.y + a1.y) + (a2.y + a3.y);
    acc.z = (a0.z + a1.z) + (a2.z + a3.z);
    acc.w = (a0.w + a1.w) + (a2.w + a3.w);

    ushort4 h4;
    h4.x = f2h(acc.x); h4.y = f2h(acc.y); h4.z = f2h(acc.z); h4.w = f2h(acc.w);
    *reinterpret_cast<ushort4*>(out + (size_t)node * 512 + 256 + (size_t)lane * 4) = h4;
}

// ---------------------------------------------------------------------------
extern "C" void kernel_launch(void* const* d_in, const int* in_sizes, int n_in,
                              void* d_out, int out_size, void* d_ws, size_t ws_size,
                              hipStream_t stream) {
    const float* x       = (const float*)d_in[0];
    const int*   edges   = (const int*)d_in[1];
    const float* pre_w1  = (const float*)d_in[2];
    const float* pre_b1  = (const float*)d_in[3];
    const float* pre_w2  = (const float*)d_in[4];
    const float* pre_b2  = (const float*)d_in[5];
    const float* conv_w  = (const float*)d_in[6];
    const float* conv_b  = (const float*)d_in[7];
    const float* post_w1 = (const float*)d_in[8];
    const float* post_b1 = (const float*)d_in[9];
    const float* post_w2 = (const float*)d_in[10];
    const float* post_b2 = (const float*)d_in[11];

    const int N = in_sizes[0] / 16;
    const int E = in_sizes[1] / 2;
    const int* src = edges;
    const int* dst = edges + E;

    const int Mp128 = (N + 127) & ~127;        // 50048: pad for 128-row tiles
    const int Mp256 = (N + 255) & ~255;        // 50176: pad for 256-row tiles

    // workspace layout (~136 MB); all GEMM-A buffers padded so DMA staging
    // never reads out of bounds (pad rows hold junk, masked at C-write)
    u16*   hcat = (u16*)d_ws;                              // Mp128 x 512 fp16
    u16*   t0   = hcat + (size_t)Mp128 * 512;              // Mp128 x 256 fp16
    u16*   tf16 = t0 + (size_t)Mp128 * 256;                // Mp128 x 256 fp16
    u16*   zbuf = tf16 + (size_t)Mp128 * 256;              // Mp256 x 256 fp16
    u16*   w2T  = zbuf + (size_t)Mp256 * 256;              // 256 x 256 fp16
    u16*   cvT  = w2T + 256 * 256;                         // 256 x 256 fp16
    u16*   p1T  = cvT + 256 * 256;                         // 256 x 512 fp16
    u16*   p2T  = p1T + 256 * 512;                         // 16 x 256 fp16
    int* offsets = (int*)(p2T + 16 * 256);                 // N+1
    int* counts  = offsets + (N + 1);                      // N
    int* cursor  = counts + N;                             // N
    int* sorted  = cursor + N;                             // E
    int* pre     = sorted + E;                             // N
    int* bsum    = pre + N;                                // <=256

    const dim3 blk(256);
    const dim3 g_mfma(Mp128 / 128, 2);                     // 391 x 2 col-blocks
    const int nsb = (N + 255) / 256;

    // weight transposes (fp16)
    wsplit_k<<<(256 * 256 + 255) / 256, blk, 0, stream>>>(pre_w2, w2T, 256, 256);
    wsplit_k<<<(256 * 256 + 255) / 256, blk, 0, stream>>>(conv_w, cvT, 256, 256);
    wsplit_k<<<(512 * 256 + 255) / 256, blk, 0, stream>>>(post_w1, p1T, 512, 256);
    wsplit_k<<<(256 * 16 + 255) / 256, blk, 0, stream>>>(post_w2, p2T, 256, 16);

    // CSR by destination
    hipMemsetAsync(counts, 0, (size_t)N * sizeof(int), stream);
    hist_k<<<(E + 255) / 256, blk, 0, stream>>>(dst, E, counts);
    scan1_k<<<nsb, blk, 0, stream>>>(counts, pre, bsum, N);
    scan2_k<<<1, blk, 0, stream>>>(bsum, nsb);
    scan3_k<<<nsb, blk, 0, stream>>>(pre, bsum, offsets, cursor, N, E);
    fill_k<<<(E + 255) / 256, blk, 0, stream>>>(src, dst, E, cursor, sorted);

    // 1. t0 = relu(x @ pre_w1 + b1) -> fp16
    pre1_k<<<(N + 15) / 16, blk, 0, stream>>>(x, pre_w1, pre_b1, t0, N);
    // 2. h = t0 @ pre_w2 + b2 -> hcat[:, :256] fp16
    mfma_k<0, 1><<<g_mfma, blk, 0, stream>>>(t0, 256, w2T, pre_b2,
                                             nullptr, hcat, 512, N, 256);
    // 3. t = relu(h @ conv_w + cb) -> tf16
    mfma_k<1, 1><<<g_mfma, blk, 0, stream>>>(hcat, 512, cvT, conv_b,
                                             nullptr, tf16, 256, N, 256);
    // 4. aggregate fp16 rows -> hcat[:, 256:]
    agg_k<<<(N + 3) / 4, blk, 0, stream>>>(tf16, offsets, sorted, hcat, N);
    // 5. z = relu(hcat @ post_w1 + b1) -> zbuf fp16
    mfma_k<1, 1><<<g_mfma, blk, 0, stream>>>(hcat, 512, p1T, post_b1,
                                             nullptr, zbuf, 256, N, 512);
    // 6. out = tanh(z @ post_w2 + b2) — fused MFMA tail
    post2_k<<<Mp256 / 256, blk, 0, stream>>>(zbuf, p2T, post_b2, (float*)d_out, N);
}

// Round 9
// 279.340 us; speedup vs baseline: 1.7458x; 1.0072x over previous
//
#include <hip/hip_runtime.h>
#include <hip/hip_bf16.h>

using f16x8 = __attribute__((ext_vector_type(8))) _Float16;  // 8 fp16 (4 VGPRs)
using f32x4 = __attribute__((ext_vector_type(4))) float;
using u16 = unsigned short;

__device__ __forceinline__ u16 f2h(float v) {
    _Float16 h = (_Float16)v;
    u16 r; __builtin_memcpy(&r, &h, 2); return r;
}
__device__ __forceinline__ float h2f(u16 x) {
    _Float16 h; __builtin_memcpy(&h, &x, 2); return (float)h;
}

// bank-decorrelation XOR: chunk permutation within a row's 4x16B chunks
__device__ __forceinline__ int fsw(int row) { return (row & 3) ^ ((row >> 2) & 3); }
__device__ __forceinline__ int aoff(int row, int kq) {
    return row * 32 + ((kq ^ fsw(row)) * 8);
}

// async global->LDS DMA, 16B per lane; LDS dest = wave-uniform base + lane*16
__device__ __forceinline__ void gl16(const u16* g, const u16* l) {
    __builtin_amdgcn_global_load_lds(
        (const __attribute__((address_space(1))) unsigned int*)g,
        (__attribute__((address_space(3))) unsigned int*)l, 16, 0, 0);
}

// ---------------------------------------------------------------------------
// fp16 MFMA GEMM (fp32 accumulate), m97-style: tile 128x128, BK=32,
// 256 threads = 4 waves (2x2), each wave owns a 64x64 output tile.
// A fp16 [Mpad][lda]; BT fp16 [Ncols][K] (transposed weights, ldb=K).
// global_load_lds staging, linear LDS, XOR swizzle applied on source AND read.
// OUTM: 0 = fp32 Cf, 1 = fp16 Ch.
// ---------------------------------------------------------------------------
template<int ACT, int OUTM>
__global__ __launch_bounds__(256, 4)
void mfma_k(const u16* __restrict__ A, int lda,
            const u16* __restrict__ BT,
            const float* __restrict__ bias,
            float* __restrict__ Cf, u16* __restrict__ Ch,
            int ldc, int M, int K) {
    __shared__ u16 As[2][128 * 32];
    __shared__ u16 Bs[2][128 * 32];

    const int tid  = threadIdx.x;
    const int brow = blockIdx.x * 128;
    const int bcol = blockIdx.y * 128;
    const int lane = tid & 63;
    const int w    = tid >> 6;
    const int wr = w >> 1, wc = w & 1;
    const int lr = lane & 15, lq = lane >> 4;

    const int r0 = w, r1 = 4 + w;
    const int row0 = r0 * 16 + (lane >> 2);
    const int row1 = r1 * 16 + (lane >> 2);
    const int s    = lane & 3;
    const int c0 = s ^ fsw(row0);
    const int c1 = s ^ fsw(row1);
    const u16* gA0 = A  + (size_t)(brow + row0) * lda + c0 * 8;
    const u16* gA1 = A  + (size_t)(brow + row1) * lda + c1 * 8;
    const u16* gB0 = BT + (size_t)(bcol + row0) * K   + c0 * 8;
    const u16* gB1 = BT + (size_t)(bcol + row1) * K   + c1 * 8;

    f32x4 acc[4][4] = {};

#define STAGE(buf, koff)                                                       \
    do {                                                                       \
        gl16(gA0 + (koff), &As[buf][r0 * 512]);                                \
        gl16(gA1 + (koff), &As[buf][r1 * 512]);                                \
        gl16(gB0 + (koff), &Bs[buf][r0 * 512]);                                \
        gl16(gB1 + (koff), &Bs[buf][r1 * 512]);                                \
    } while (0)

    STAGE(0, 0);
    __syncthreads();

    const int nt = K >> 5;
    int cur = 0;
    for (int t = 0; t < nt; ++t) {
        if (t + 1 < nt) STAGE(cur ^ 1, (t + 1) * 32);

        f16x8 bf[4];
        #pragma unroll
        for (int n = 0; n < 4; ++n)
            bf[n] = *reinterpret_cast<const f16x8*>(&Bs[cur][aoff(wc * 64 + n * 16 + lr, lq)]);
        #pragma unroll
        for (int m = 0; m < 4; ++m) {
            f16x8 af = *reinterpret_cast<const f16x8*>(&As[cur][aoff(wr * 64 + m * 16 + lr, lq)]);
            #pragma unroll
            for (int n = 0; n < 4; ++n)
                acc[m][n] = __builtin_amdgcn_mfma_f32_16x16x32_f16(af, bf[n], acc[m][n], 0, 0, 0);
        }

        if (t + 1 < nt) {
            __syncthreads();
            cur ^= 1;
        }
    }
#undef STAGE

    #pragma unroll
    for (int m = 0; m < 4; ++m) {
        #pragma unroll
        for (int n = 0; n < 4; ++n) {
            #pragma unroll
            for (int r = 0; r < 4; ++r) {
                int grow = brow + wr * 64 + m * 16 + lq * 4 + r;
                if (grow >= M) continue;
                int gcol = bcol + wc * 64 + n * 16 + lr;
                float v = acc[m][n][r] + bias[gcol];
                if (ACT == 1) v = fmaxf(v, 0.f);
                size_t o = (size_t)grow * ldc + gcol;
                if (OUTM == 0) Cf[o] = v;
                else           Ch[o] = f2h(v);
            }
        }
    }
}

// ---------------------------------------------------------------------------
// Final layer fused: out = tanh(Z @ p2 + b2), Z fp16 [*][256], p2T fp16 [16][256].
// ---------------------------------------------------------------------------
__global__ __launch_bounds__(256, 4)
void post2_k(const u16* __restrict__ Z, const u16* __restrict__ P2T,
             const float* __restrict__ b2, float* __restrict__ out, int M) {
    __shared__ u16 As[2][256 * 32];

    const int tid  = threadIdx.x;
    const int brow = blockIdx.x * 256;
    const int lane = tid & 63;
    const int w    = tid >> 6;
    const int lr = lane & 15, lq = lane >> 4;

    f16x8 bfr[8];
    #pragma unroll
    for (int kk = 0; kk < 8; ++kk)
        bfr[kk] = *reinterpret_cast<const f16x8*>(P2T + lr * 256 + kk * 32 + lq * 8);

    int rows[4]; int cs[4]; const u16* gz[4];
    #pragma unroll
    for (int i = 0; i < 4; ++i) {
        int r = i * 4 + w;
        rows[i] = r * 16 + (lane >> 2);
        cs[i]   = (lane & 3) ^ fsw(rows[i]);
        gz[i]   = Z + (size_t)(brow + rows[i]) * 256 + cs[i] * 8;
    }

#define STAGEZ(buf, koff)                                                      \
    do {                                                                       \
        _Pragma("unroll")                                                      \
        for (int i = 0; i < 4; ++i)                                            \
            gl16(gz[i] + (koff), &As[buf][(i * 4 + w) * 512]);                 \
    } while (0)

    f32x4 acc[4] = {};

    STAGEZ(0, 0);
    __syncthreads();

    #pragma unroll
    for (int t = 0; t < 8; ++t) {
        if (t < 7) STAGEZ((t + 1) & 1, (t + 1) * 32);
        #pragma unroll
        for (int m = 0; m < 4; ++m) {
            f16x8 af = *reinterpret_cast<const f16x8*>(&As[t & 1][aoff(w * 64 + m * 16 + lr, lq)]);
            acc[m] = __builtin_amdgcn_mfma_f32_16x16x32_f16(af, bfr[t], acc[m], 0, 0, 0);
        }
        if (t < 7) __syncthreads();
    }
#undef STAGEZ

    const float b = b2[lr];
    #pragma unroll
    for (int m = 0; m < 4; ++m) {
        #pragma unroll
        for (int r = 0; r < 4; ++r) {
            int grow = brow + w * 64 + m * 16 + lq * 4 + r;
            if (grow >= M) continue;
            out[(size_t)grow * 16 + lr] = tanhf(acc[m][r] + b);
        }
    }
}

// ---------------------------------------------------------------------------
// Layer 1 (K=16): t0 = relu(x @ pre_w1 + b1) -> fp16, row stride ldc
// ---------------------------------------------------------------------------
__global__ __launch_bounds__(256)
void pre1_k(const float* __restrict__ x, const float* __restrict__ w1,
            const float* __restrict__ b1,
            u16* __restrict__ t0, int ldc, int M) {
    __shared__ float ws[16 * 256];
    __shared__ float xs[16][17];
    const int tid = threadIdx.x;
    for (int i = tid; i < 16 * 256; i += 256) ws[i] = w1[i];
    const int r0 = blockIdx.x * 16;
    {
        int rr = tid >> 4, cc = tid & 15;
        xs[rr][cc] = (r0 + rr < M) ? x[(size_t)(r0 + rr) * 16 + cc] : 0.f;
    }
    __syncthreads();
    const int c = tid;
    const float b = b1[c];
    for (int r = 0; r < 16; r++) {
        if (r0 + r >= M) break;
        float acc = b;
        #pragma unroll
        for (int k = 0; k < 16; k++) acc = fmaf(xs[r][k], ws[k * 256 + c], acc);
        t0[(size_t)(r0 + r) * ldc + c] = f2h(fmaxf(acc, 0.f));
    }
}

// ---------------------------------------------------------------------------
// Combined-weight builder: WT[n*ldout + koff + k] = fp16( (A@B)[k][n] ),
// plus a fused bias row: biasOut[n] = (avec@B)[n] + addv[n].
// A [256][256] f32 row-major; B [256][ldb] f32 (rows 0..255 used).
// grid = 257 blocks x 256 threads; block 256 computes the bias row.
// ---------------------------------------------------------------------------
__global__ __launch_bounds__(256)
void wcombT_k(const float* __restrict__ A, const float* __restrict__ avec,
              const float* __restrict__ B, int ldb,
              const float* __restrict__ addv,
              u16* __restrict__ WT, int ldout, int koff,
              float* __restrict__ biasOut) {
    __shared__ float a_sh[256];
    const int k = blockIdx.x;
    const int n = threadIdx.x;
    const bool isBias = (k == 256);
    a_sh[n] = isBias ? avec[n] : A[(size_t)k * 256 + n];
    __syncthreads();
    float s = 0.f;
    #pragma unroll 8
    for (int j = 0; j < 256; ++j)
        s = fmaf(a_sh[j], B[(size_t)j * ldb + n], s);
    if (isBias) biasOut[n] = s + addv[n];
    else        WT[(size_t)n * ldout + koff + k] = f2h(s);
}

// P1a transpose: zWT[n*512 + 256 + k] = fp16(post_w1[256+k][n])
__global__ void p1aT_k(const float* __restrict__ P1, u16* __restrict__ zWT) {
    int i = blockIdx.x * blockDim.x + threadIdx.x;   // 65536
    int n = i >> 8, k = i & 255;
    zWT[(size_t)n * 512 + 256 + k] = f2h(P1[(size_t)(256 + k) * 256 + n]);
}

// weight transpose + fp16 cast: W [K][N] fp32 -> WT [N][K] fp16
__global__ void wsplit_k(const float* __restrict__ W, u16* __restrict__ WT,
                         int K, int N) {
    int i = blockIdx.x * blockDim.x + threadIdx.x;
    if (i >= K * N) return;
    int n = i / K, k = i % K;
    WT[i] = f2h(W[(size_t)k * N + n]);
}

// ---------------------------------------------------------------------------
// CSR-by-destination build
// ---------------------------------------------------------------------------
__global__ void hist_k(const int* __restrict__ dst, int E, int* __restrict__ counts) {
    int i = blockIdx.x * blockDim.x + threadIdx.x;
    if (i < E) atomicAdd(&counts[dst[i]], 1);
}

__global__ __launch_bounds__(256)
void scan1_k(const int* __restrict__ counts, int* __restrict__ pre,
             int* __restrict__ bsum, int n) {
    __shared__ int sh[256];
    const int t = threadIdx.x;
    const int i = blockIdx.x * 256 + t;
    int v = (i < n) ? counts[i] : 0;
    sh[t] = v;
    __syncthreads();
    #pragma unroll
    for (int d = 1; d < 256; d <<= 1) {
        int x = (t >= d) ? sh[t - d] : 0;
        __syncthreads();
        sh[t] += x;
        __syncthreads();
    }
    if (i < n) pre[i] = sh[t] - v;
    if (t == 255) bsum[blockIdx.x] = sh[255];
}

__global__ __launch_bounds__(256)
void scan2_k(int* __restrict__ bsum, int nb) {
    __shared__ int sh[256];
    const int t = threadIdx.x;
    int v = (t < nb) ? bsum[t] : 0;
    sh[t] = v;
    __syncthreads();
    #pragma unroll
    for (int d = 1; d < 256; d <<= 1) {
        int x = (t >= d) ? sh[t - d] : 0;
        __syncthreads();
        sh[t] += x;
        __syncthreads();
    }
    if (t < nb) bsum[t] = sh[t] - v;
}

__global__ __launch_bounds__(256)
void scan3_k(const int* __restrict__ pre, const int* __restrict__ bsum,
             int* __restrict__ offsets, int* __restrict__ cursor,
             int n, int total) {
    const int i = blockIdx.x * 256 + threadIdx.x;
    if (i < n) {
        int o = pre[i] + bsum[blockIdx.x];
        offsets[i] = o;
        cursor[i]  = o;
    }
    if (i == 0) offsets[n] = total;
}

__global__ void fill_k(const int* __restrict__ src, const int* __restrict__ dst, int E,
                       int* __restrict__ cursor, int* __restrict__ sorted_src) {
    int i = blockIdx.x * blockDim.x + threadIdx.x;
    if (i < E) {
        int d = dst[i];
        int pos = atomicAdd(&cursor[d], 1);
        sorted_src[pos] = src[i];
    }
}

// ---------------------------------------------------------------------------
// Aggregate fp16 message rows (512 B), fp32 accumulate, fp16 out into
// hcat cols 256..511. Unroll-8: 8 independent row loads in flight per wave.
// ---------------------------------------------------------------------------
__global__ void agg_k(const u16* __restrict__ t, const int* __restrict__ offsets,
                      const int* __restrict__ sorted_src,
                      u16* __restrict__ out, int n) {
    const int node = blockIdx.x * (blockDim.x >> 6) + (threadIdx.x >> 6);
    const int lane = threadIdx.x & 63;
    if (node >= n) return;
    const int s0 = offsets[node], s1 = offsets[node + 1];

    float4 a0 = make_float4(0.f, 0.f, 0.f, 0.f);
    float4 a1 = a0, a2 = a0, a3 = a0;

    int i = s0;
    for (; i + 8 <= s1; i += 8) {
        int e0 = sorted_src[i];
        int e1 = sorted_src[i + 1];
        int e2 = sorted_src[i + 2];
        int e3 = sorted_src[i + 3];
        int e4 = sorted_src[i + 4];
        int e5 = sorted_src[i + 5];
        int e6 = sorted_src[i + 6];
        int e7 = sorted_src[i + 7];
        ushort4 v0 = *reinterpret_cast<const ushort4*>(t + (size_t)e0 * 256 + lane * 4);
        ushort4 v1 = *reinterpret_cast<const ushort4*>(t + (size_t)e1 * 256 + lane * 4);
        ushort4 v2 = *reinterpret_cast<const ushort4*>(t + (size_t)e2 * 256 + lane * 4);
        ushort4 v3 = *reinterpret_cast<const ushort4*>(t + (size_t)e3 * 256 + lane * 4);
        ushort4 v4 = *reinterpret_cast<const ushort4*>(t + (size_t)e4 * 256 + lane * 4);
        ushort4 v5 = *reinterpret_cast<const ushort4*>(t + (size_t)e5 * 256 + lane * 4);
        ushort4 v6 = *reinterpret_cast<const ushort4*>(t + (size_t)e6 * 256 + lane * 4);
        ushort4 v7 = *reinterpret_cast<const ushort4*>(t + (size_t)e7 * 256 + lane * 4);
        a0.x += h2f(v0.x); a0.y += h2f(v0.y); a0.z += h2f(v0.z); a0.w += h2f(v0.w);
        a1.x += h2f(v1.x); a1.y += h2f(v1.y); a1.z += h2f(v1.z); a1.w += h2f(v1.w);
        a2.x += h2f(v2.x); a2.y += h2f(v2.y); a2.z += h2f(v2.z); a2.w += h2f(v2.w);
        a3.x += h2f(v3.x); a3.y += h2f(v3.y); a3.z += h2f(v3.z); a3.w += h2f(v3.w);
        a0.x += h2f(v4.x); a0.y += h2f(v4.y); a0.z += h2f(v4.z); a0.w += h2f(v4.w);
        a1.x += h2f(v5.x); a1.y += h2f(v5.y); a1.z += h2f(v5.z); a1.w += h2f(v5.w);
        a2.x += h2f(v6.x); a2.y += h2f(v6.y); a2.z += h2f(v6.z); a2.w += h2f(v6.w);
        a3.x += h2f(v7.x); a3.y += h2f(v7.y); a3.z += h2f(v7.z); a3.w += h2f(v7.w);
    }
    for (; i + 4 <= s1; i += 4) {
        int e0 = sorted_src[i];
        int e1 = sorted_src[i + 1];
        int e2 = sorted_src[i + 2];
        int e3 = sorted_src[i + 3];
        ushort4 v0 = *reinterpret_cast<const ushort4*>(t + (size_t)e0 * 256 + lane * 4);
        ushort4 v1 = *reinterpret_cast<const ushort4*>(t + (size_t)e1 * 256 + lane * 4);
        ushort4 v2 = *reinterpret_cast<const ushort4*>(t + (size_t)e2 * 256 + lane * 4);
        ushort4 v3 = *reinterpret_cast<const ushort4*>(t + (size_t)e3 * 256 + lane * 4);
        a0.x += h2f(v0.x); a0.y += h2f(v0.y); a0.z += h2f(v0.z); a0.w += h2f(v0.w);
        a1.x += h2f(v1.x); a1.y += h2f(v1.y); a1.z += h2f(v1.z); a1.w += h2f(v1.w);
        a2.x += h2f(v2.x); a2.y += h2f(v2.y); a2.z += h2f(v2.z); a2.w += h2f(v2.w);
        a3.x += h2f(v3.x); a3.y += h2f(v3.y); a3.z += h2f(v3.z); a3.w += h2f(v3.w);
    }
    for (; i < s1; ++i) {
        int e0 = sorted_src[i];
        ushort4 v0 = *reinterpret_cast<const ushort4*>(t + (size_t)e0 * 256 + lane * 4);
        a0.x += h2f(v0.x); a0.y += h2f(v0.y); a0.z += h2f(v0.z); a0.w += h2f(v0.w);
    }
    float4 acc;
    acc.x = (a0.x + a1.x) + (a2.x + a3.x);
    acc.y = (a0.y + a1.y) + (a2.y + a3.y);
    acc.z = (a0.z + a1.z) + (a2.z + a3.z);
    acc.w = (a0.w + a1.w) + (a2.w + a3.w);

    ushort4 h4;
    h4.x = f2h(acc.x); h4.y = f2h(acc.y); h4.z = f2h(acc.z); h4.w = f2h(acc.w);
    *reinterpret_cast<ushort4*>(out + (size_t)node * 512 + 256 + (size_t)lane * 4) = h4;
}

// ---------------------------------------------------------------------------
extern "C" void kernel_launch(void* const* d_in, const int* in_sizes, int n_in,
                              void* d_out, int out_size, void* d_ws, size_t ws_size,
                              hipStream_t stream) {
    const float* x       = (const float*)d_in[0];
    const int*   edges   = (const int*)d_in[1];
    const float* pre_w1  = (const float*)d_in[2];
    const float* pre_b1  = (const float*)d_in[3];
    const float* pre_w2  = (const float*)d_in[4];
    const float* pre_b2  = (const float*)d_in[5];
    const float* conv_w  = (const float*)d_in[6];
    const float* conv_b  = (const float*)d_in[7];
    const float* post_w1 = (const float*)d_in[8];
    const float* post_b1 = (const float*)d_in[9];
    const float* post_w2 = (const float*)d_in[10];
    const float* post_b2 = (const float*)d_in[11];

    const int N = in_sizes[0] / 16;
    const int E = in_sizes[1] / 2;
    const int* src = edges;
    const int* dst = edges + E;

    const int Mp128 = (N + 127) & ~127;        // pad for 128-row tiles
    const int Mp256 = (N + 255) & ~255;        // pad for 256-row tiles

    // workspace layout (~107 MB)
    u16*   hcat = (u16*)d_ws;                              // Mp128 x 512 fp16: [t0 | agg]
    u16*   tf16 = hcat + (size_t)Mp128 * 512;              // Mp128 x 256 fp16
    u16*   zbuf = tf16 + (size_t)Mp128 * 256;              // Mp256 x 256 fp16
    u16*   wcT  = zbuf + (size_t)Mp256 * 256;              // 256 x 256 fp16 (W2@Wc)^T
    u16*   zWT  = wcT + 256 * 256;                         // 256 x 512 fp16 [(W2@P1h)^T | P1a^T]
    u16*   p2T  = zWT + 256 * 512;                         // 16 x 256 fp16
    float* btc  = (float*)(p2T + 16 * 256);                // 256 f32 (b2@Wc + cb)
    float* bzc  = btc + 256;                               // 256 f32 (b2@P1h + b1)
    int* offsets = (int*)(bzc + 256);                      // N+1
    int* counts  = offsets + (N + 1);                      // N
    int* cursor  = counts + N;                             // N
    int* sorted  = cursor + N;                             // E
    int* pre     = sorted + E;                             // N
    int* bsum    = pre + N;                                // <=256

    const dim3 blk(256);
    const dim3 g_mfma(Mp128 / 128, 2);
    const int nsb = (N + 255) / 256;

    // combined weights (h eliminated algebraically):
    //   t = relu(t0 @ (W2@Wc) + (b2@Wc + cb))
    //   z = relu(t0 @ (W2@P1h) + agg @ P1a + (b2@P1h + b1))
    wcombT_k<<<257, blk, 0, stream>>>(pre_w2, pre_b2, conv_w, 256, conv_b,
                                      wcT, 256, 0, btc);
    wcombT_k<<<257, blk, 0, stream>>>(pre_w2, pre_b2, post_w1, 256, post_b1,
                                      zWT, 512, 0, bzc);
    p1aT_k<<<256, blk, 0, stream>>>(post_w1, zWT);
    wsplit_k<<<(256 * 16 + 255) / 256, blk, 0, stream>>>(post_w2, p2T, 256, 16);

    // CSR by destination
    hipMemsetAsync(counts, 0, (size_t)N * sizeof(int), stream);
    hist_k<<<(E + 255) / 256, blk, 0, stream>>>(dst, E, counts);
    scan1_k<<<nsb, blk, 0, stream>>>(counts, pre, bsum, N);
    scan2_k<<<1, blk, 0, stream>>>(bsum, nsb);
    scan3_k<<<nsb, blk, 0, stream>>>(pre, bsum, offsets, cursor, N, E);
    fill_k<<<(E + 255) / 256, blk, 0, stream>>>(src, dst, E, cursor, sorted);

    // 1. t0 = relu(x @ pre_w1 + b1) -> hcat[:, :256] fp16
    pre1_k<<<(N + 15) / 16, blk, 0, stream>>>(x, pre_w1, pre_b1, hcat, 512, N);
    // 2. t = relu(t0 @ Wcomb + btc) -> tf16
    mfma_k<1, 1><<<g_mfma, blk, 0, stream>>>(hcat, 512, wcT, btc,
                                             nullptr, tf16, 256, N, 256);
    // 3. aggregate fp16 rows -> hcat[:, 256:]
    agg_k<<<(N + 3) / 4, blk, 0, stream>>>(tf16, offsets, sorted, hcat, N);
    // 4. z = relu([t0|agg] @ [Q;P1a] + bzc) -> zbuf fp16
    mfma_k<1, 1><<<g_mfma, blk, 0, stream>>>(hcat, 512, zWT, bzc,
                                             nullptr, zbuf, 256, N, 512);
    // 5. out = tanh(z @ post_w2 + b2) — fused MFMA tail
    post2_k<<<Mp256 / 256, blk, 0, stream>>>(zbuf, p2T, post_b2, (float*)d_out, N);
}